// Round 4
// baseline (1551.333 us; speedup 1.0000x reference)
//
#include <hip/hip_runtime.h>
#include <hip/hip_bf16.h>

#define NND 50000
#define NE 800000
#define NM 2
#define INF 256
#define NH 4
#define HDIM 256
#define SHID 128
#define SLOPE 0.2f

typedef unsigned short u16;
typedef __attribute__((ext_vector_type(8))) short bf16x8;
typedef __attribute__((ext_vector_type(4))) float f32x4;

__device__ __forceinline__ float us2f(u16 u) {
  union { unsigned int i; float f; } v; v.i = ((unsigned int)u) << 16; return v.f;
}
__device__ __forceinline__ u16 f2us(float f) {
  union { float f; unsigned int i; } v; v.f = f;
  unsigned int r = v.i + 0x7FFFu + ((v.i >> 16) & 1u);
  return (u16)(r >> 16);
}

template<int BF> __device__ __forceinline__ float ldf(const void* p, size_t i) {
  return BF ? us2f(((const u16*)p)[i]) : ((const float*)p)[i];
}

#define GLDS(g, l) __builtin_amdgcn_global_load_lds( \
    (const __attribute__((address_space(1))) unsigned int*)(g), \
    (__attribute__((address_space(3))) unsigned int*)(l), 16, 0, 0)

// k0: detect float dtype of inputs. bf16 -> flag=1, f32 -> flag=0.
__global__ void k0_detect(const u16* __restrict__ h, int* __restrict__ flag) {
  if (threadIdx.x == 0 && blockIdx.x == 0) {
    int hits = 0;
    for (int i = 0; i < 256; ++i) {
      int e = (h[i] >> 7) & 0xFF;
      if (e >= 100 && e <= 140) hits++;
    }
    *flag = (hits >= 200) ? 1 : 0;
  }
}

// ---------------- CSR build ----------------
__global__ __launch_bounds__(256) void kc_hist(const int* __restrict__ dst,
                                               int* __restrict__ rowptr) {
  int e = blockIdx.x * 256 + threadIdx.x;
  if (e < NE) atomicAdd(rowptr + dst[e] + 1, 1);
}

__global__ __launch_bounds__(1024) void kc_scan(int* __restrict__ rowptr) {
  __shared__ int sums[1024];
  const int t = threadIdx.x;
  const int CH = 49;
  int lo = 1 + t * CH;
  int hi = lo + CH; if (hi > NND + 1) hi = NND + 1;
  int local = 0;
  for (int i = lo; i < hi; ++i) local += rowptr[i];
  sums[t] = local;
  __syncthreads();
  for (int s = 1; s < 1024; s <<= 1) {
    int v = (t >= s) ? sums[t - s] : 0;
    __syncthreads();
    sums[t] += v;
    __syncthreads();
  }
  int running = sums[t] - local;
  for (int i = lo; i < hi; ++i) {
    running += rowptr[i];
    rowptr[i] = running;
  }
}

__global__ __launch_bounds__(256) void kc_scatter(const int* __restrict__ src,
                                                  const int* __restrict__ dst,
                                                  int* __restrict__ cursor,
                                                  int* __restrict__ col) {
  int e = blockIdx.x * 256 + threadIdx.x;
  if (e >= NE) return;
  int pos = atomicAdd(cursor + dst[e], 1);
  col[pos] = src[e];
}

// ---------------- W transpose: Wt[m][n][k] = W[m][k][n] (bf16 path) --------
__global__ __launch_bounds__(256) void kt_transpose(
    const int* __restrict__ flag, const u16* __restrict__ W, u16* __restrict__ Wt)
{
  if (*flag != 1) return;
  __shared__ u16 tile[64][65];
  const int t = threadIdx.x;
  const int k0 = blockIdx.x * 64;
  const int n0 = blockIdx.y * 64;
  const u16* Wm = W + (size_t)blockIdx.z * 65536;
  u16* Wtm = Wt + (size_t)blockIdx.z * 65536;
  const int lr = t >> 2, c0 = (t & 3) * 16;
#pragma unroll
  for (int i = 0; i < 16; ++i)
    tile[lr][c0 + i] = Wm[(size_t)(k0 + lr) * 256 + n0 + c0 + i];
  __syncthreads();
#pragma unroll
  for (int i = 0; i < 16; ++i)
    Wtm[(size_t)(n0 + lr) * 256 + k0 + c0 + i] = tile[c0 + i][lr];
}

// ---------------- K1 (bf16): feat = h @ W[m] via MFMA ----------------------
// 128x128 tile, BK=32, 4 waves (2x2), each wave 64x64 = 4x4 16x16 fragments.
__global__ __launch_bounds__(256) void k1_mfma(
    const int* __restrict__ flag, const u16* __restrict__ h,
    const u16* __restrict__ Wt, u16* __restrict__ feat)
{
  if (*flag != 1) return;
  __shared__ u16 As[128 * 32];
  __shared__ u16 Bs[128 * 32];
  const int t = threadIdx.x;
  const int lane = t & 63;
  const int w = t >> 6;
  const int wr = w >> 1, wc = w & 1;
  const int row0 = blockIdx.x * 128;
  const int col0 = blockIdx.y * 128;

  const int sr = t >> 2;            // staging row within 64-row half
  const int skb = (t & 3) * 8;      // staging k element offset

  int ra0 = row0 + sr;       if (ra0 >= NND) ra0 = NND - 1;   // clamp tail (dupes ok)
  int ra1 = row0 + 64 + sr;  if (ra1 >= NND) ra1 = NND - 1;
  const int cb0 = col0 + sr, cb1 = col0 + 64 + sr;

  f32x4 acc[4][4];
#pragma unroll
  for (int i = 0; i < 4; ++i)
#pragma unroll
    for (int j = 0; j < 4; ++j) acc[i][j] = (f32x4){0.f, 0.f, 0.f, 0.f};

  for (int ks = 0; ks < 8; ++ks) {
    const int kb = ks * 32 + skb;
    __syncthreads();                       // LDS safe to overwrite
    GLDS(h + (size_t)ra0 * INF + kb, As + w * 512);
    GLDS(h + (size_t)ra1 * INF + kb, As + 2048 + w * 512);
    GLDS(Wt + (size_t)cb0 * 256 + kb, Bs + w * 512);
    GLDS(Wt + (size_t)cb1 * 256 + kb, Bs + 2048 + w * 512);
    __syncthreads();                       // drains vmcnt before barrier
    bf16x8 af[4], bfr[4];
#pragma unroll
    for (int mi = 0; mi < 4; ++mi)
      af[mi] = *(const bf16x8*)(As + (wr * 64 + mi * 16 + (lane & 15)) * 32 + (lane >> 4) * 8);
#pragma unroll
    for (int ni = 0; ni < 4; ++ni)
      bfr[ni] = *(const bf16x8*)(Bs + (wc * 64 + ni * 16 + (lane & 15)) * 32 + (lane >> 4) * 8);
#pragma unroll
    for (int mi = 0; mi < 4; ++mi)
#pragma unroll
      for (int ni = 0; ni < 4; ++ni)
        acc[mi][ni] = __builtin_amdgcn_mfma_f32_16x16x32_bf16(af[mi], bfr[ni], acc[mi][ni], 0, 0, 0);
  }
  // epilogue: C layout col=lane&15, row=(lane>>4)*4+i  [m89/m91]
#pragma unroll
  for (int mi = 0; mi < 4; ++mi) {
    const int r_base = row0 + wr * 64 + mi * 16 + (lane >> 4) * 4;
#pragma unroll
    for (int i = 0; i < 4; ++i) {
      const int r = r_base + i;
      if (r < NND) {
#pragma unroll
        for (int ni = 0; ni < 4; ++ni) {
          const int c = col0 + wc * 64 + ni * 16 + (lane & 15);
          feat[(size_t)r * HDIM + c] = f2us(acc[mi][ni][i]);
        }
      }
    }
  }
}

// ---------------- K1b (bf16): el/er from feat ------------------------------
__global__ __launch_bounds__(256) void k1b_elr(
    const int* __restrict__ flag, const u16* __restrict__ feat,
    const u16* __restrict__ al, const u16* __restrict__ ar,
    float* __restrict__ el, float* __restrict__ er, int m)
{
  if (*flag != 1) return;
  const int n = blockIdx.x * 4 + (threadIdx.x >> 6);
  const int lane = threadIdx.x & 63;
  ushort4 f4 = *(const ushort4*)(feat + (size_t)n * HDIM + lane * 4);
  ushort4 a4 = *(const ushort4*)(al + m * HDIM + lane * 4);
  ushort4 r4 = *(const ushort4*)(ar + m * HDIM + lane * 4);
  float fl = us2f(f4.x) * us2f(a4.x) + us2f(f4.y) * us2f(a4.y)
           + us2f(f4.z) * us2f(a4.z) + us2f(f4.w) * us2f(a4.w);
  float fr = us2f(f4.x) * us2f(r4.x) + us2f(f4.y) * us2f(r4.y)
           + us2f(f4.z) * us2f(r4.z) + us2f(f4.w) * us2f(r4.w);
#pragma unroll
  for (int o = 1; o < 16; o <<= 1) {
    fl += __shfl_xor(fl, o, 64);
    fr += __shfl_xor(fr, o, 64);
  }
  if ((lane & 15) == 0) {
    el[n * 4 + (lane >> 4)] = fl;
    er[n * 4 + (lane >> 4)] = fr;
  }
}

// ---------------- K1 (f32 fallback): VALU gemm + el/er ---------------------
template<int BF>
__global__ __launch_bounds__(256) void k1_gemm(
    const int* __restrict__ flag,
    const void* __restrict__ h, const void* __restrict__ W,
    const void* __restrict__ al, const void* __restrict__ ar,
    u16* __restrict__ feat, float* __restrict__ el, float* __restrict__ er,
    int m)
{
  if (*flag != BF) return;
  const int t = threadIdx.x;
  const int n0 = blockIdx.x * 16;
  const size_t wbase = (size_t)m * INF * HDIM;
  float acc[16];
#pragma unroll
  for (int i = 0; i < 16; ++i) acc[i] = 0.f;
  for (int k = 0; k < INF; ++k) {
    float w = ldf<BF>(W, wbase + (size_t)k * HDIM + t);
#pragma unroll
    for (int nn = 0; nn < 16; ++nn)
      acc[nn] = fmaf(ldf<BF>(h, (size_t)(n0 + nn) * INF + k), w, acc[nn]);
  }
  const int lane = t & 63;
  const int head = t >> 6;
  const float alv = ldf<BF>(al, (size_t)m * HDIM + t);
  const float arv = ldf<BF>(ar, (size_t)m * HDIM + t);
#pragma unroll
  for (int nn = 0; nn < 16; ++nn) {
    float f = acc[nn];
    feat[(size_t)(n0 + nn) * HDIM + t] = f2us(f);
    float cl = f * alv;
    float cr = f * arv;
#pragma unroll
    for (int o = 32; o; o >>= 1) {
      cl += __shfl_xor(cl, o, 64);
      cr += __shfl_xor(cr, o, 64);
    }
    if (lane == 0) {
      el[(n0 + nn) * NH + head] = cl;
      er[(n0 + nn) * NH + head] = cr;
    }
  }
}

// ---------------- K3: CSR gather (fused den + aggregate + elu + z store) ----
template<int OBF>
__global__ __launch_bounds__(256) void k3_gather(
    const int* __restrict__ flag, int gate,
    const int* __restrict__ rowptr, const int* __restrict__ col,
    const float* __restrict__ el, const float* __restrict__ er,
    const u16* __restrict__ feat, void* __restrict__ z)
{
  if (gate >= 0 && *flag != gate) return;
  const int d = blockIdx.x * 4 + (threadIdx.x >> 6);
  if (d >= NND) return;
  const int lane = threadIdx.x & 63;
  const int h = lane >> 4;
  const int beg = rowptr[d], end = rowptr[d + 1];
  const float erh = er[d * 4 + h];
  float den = 0.f;
  for (int j = beg; j < end; ++j) {
    int s = col[j];
    float x = el[s * 4 + h] + erh;
    x = x > 0.f ? x : SLOPE * x;
    den += expf(x);
  }
  const float inv = 1.f / fmaxf(den, 1e-9f);
  float a0 = 0.f, a1 = 0.f, a2 = 0.f, a3 = 0.f;
  for (int j = beg; j < end; ++j) {
    int s = col[j];
    float x = el[s * 4 + h] + erh;
    x = x > 0.f ? x : SLOPE * x;
    float alpha = expf(x) * inv;
    const ushort4 f4 = *(const ushort4*)(feat + (size_t)s * HDIM + lane * 4);
    a0 = fmaf(alpha, us2f(f4.x), a0);
    a1 = fmaf(alpha, us2f(f4.y), a1);
    a2 = fmaf(alpha, us2f(f4.z), a2);
    a3 = fmaf(alpha, us2f(f4.w), a3);
  }
  a0 = a0 > 0.f ? a0 : expf(a0) - 1.f;
  a1 = a1 > 0.f ? a1 : expf(a1) - 1.f;
  a2 = a2 > 0.f ? a2 : expf(a2) - 1.f;
  a3 = a3 > 0.f ? a3 : expf(a3) - 1.f;
  const size_t idx = (size_t)d * HDIM + lane * 4;
  if (OBF) {
    ushort4 r; r.x = f2us(a0); r.y = f2us(a1); r.z = f2us(a2); r.w = f2us(a3);
    *(ushort4*)((u16*)z + idx) = r;
  } else {
    float4 r; r.x = a0; r.y = a1; r.z = a2; r.w = a3;
    *(float4*)((float*)z + idx) = r;
  }
}

// ---------------- K4: semantic score accumulation --------------------------
template<int BF>
__global__ __launch_bounds__(256) void k4_sem(
    const int* __restrict__ flag,
    const void* __restrict__ z, const void* __restrict__ w1,
    const void* __restrict__ b1, const void* __restrict__ w2,
    float* __restrict__ wsum, int midx)
{
  if (*flag != BF) return;
  __shared__ float zl[2][HDIM];
  __shared__ float red[4];
  const int t = threadIdx.x;
  const int half = t >> 7;
  const int jj = t & 127;
  const int zisf32 = (midx == 0 && BF == 0);
  const float b1f = ldf<BF>(b1, jj);
  const float w2f = ldf<BF>(w2, jj);
  float local = 0.f;
  for (int pp = 0; pp < 4; ++pp) {
    const int nbase = blockIdx.x * 8 + pp * 2;
    __syncthreads();
#pragma unroll
    for (int j = 0; j < 2; ++j) {
      const size_t idx = (size_t)(nbase + j) * HDIM + t;
      zl[j][t] = zisf32 ? ((const float*)z)[idx] : us2f(((const u16*)z)[idx]);
    }
    __syncthreads();
    float acc = 0.f;
    const float* zr = zl[half];
    for (int k = 0; k < HDIM; ++k)
      acc = fmaf(zr[k], ldf<BF>(w1, (size_t)k * SHID + jj), acc);
    local += tanhf(acc + b1f) * w2f;
  }
#pragma unroll
  for (int o = 32; o; o >>= 1) local += __shfl_xor(local, o, 64);
  const int lane = t & 63, wv = t >> 6;
  if (lane == 0) red[wv] = local;
  __syncthreads();
  if (t == 0) unsafeAtomicAdd(wsum + midx, red[0] + red[1] + red[2] + red[3]);
}

// ---------------- K5: out = b0*z0 + b1*z1 ----------------------------------
template<int BF>
__global__ __launch_bounds__(256) void k5_out(
    const int* __restrict__ flag,
    void* __restrict__ out, const u16* __restrict__ z1,
    const float* __restrict__ wsum)
{
  if (*flag != BF) return;
  const int i = blockIdx.x * 256 + threadIdx.x;
  float w0 = wsum[0] * (1.0f / NND);
  float w1v = wsum[1] * (1.0f / NND);
  float mx = fmaxf(w0, w1v);
  float e0 = expf(w0 - mx), e1 = expf(w1v - mx);
  float inv = 1.f / (e0 + e1);
  float b0 = e0 * inv, b1 = e1 * inv;
  ushort4 zb = ((const ushort4*)z1)[i];
  if (BF) {
    ushort4 a = ((const ushort4*)out)[i];
    ushort4 r;
    r.x = f2us(b0 * us2f(a.x) + b1 * us2f(zb.x));
    r.y = f2us(b0 * us2f(a.y) + b1 * us2f(zb.y));
    r.z = f2us(b0 * us2f(a.z) + b1 * us2f(zb.z));
    r.w = f2us(b0 * us2f(a.w) + b1 * us2f(zb.w));
    ((ushort4*)out)[i] = r;
  } else {
    float4 a = ((const float4*)out)[i];
    float4 r;
    r.x = b0 * a.x + b1 * us2f(zb.x);
    r.y = b0 * a.y + b1 * us2f(zb.y);
    r.z = b0 * a.z + b1 * us2f(zb.z);
    r.w = b0 * a.w + b1 * us2f(zb.w);
    ((float4*)out)[i] = r;
  }
}

extern "C" void kernel_launch(void* const* d_in, const int* in_sizes, int n_in,
                              void* d_out, int out_size, void* d_ws, size_t ws_size,
                              hipStream_t stream)
{
  const int* src = (const int*)d_in[1];
  const int* dst = (const int*)d_in[2];

  // workspace layout (bytes)
  char* wsb = (char*)d_ws;
  u16*   feat   = (u16*)(wsb);                 // 25,600,000
  u16*   z1     = (u16*)(wsb + 25600000);      // 25,600,000
  int*   col    = (int*)(wsb + 51200000);      //  3,200,000
  u16*   Wt     = (u16*)(wsb + 54400000);      //    262,144 (2x256x256 bf16)
  float* el     = (float*)(wsb + 54662144);    //    800,000
  float* er     = (float*)(wsb + 55462144);    //    800,000
  int*   rowptr = (int*)(wsb + 56262144);      //    200,004
  int*   cursor = (int*)(wsb + 56462148);      //    200,000
  float* wsum   = (float*)(wsb + 56662148);    //          8
  int*   flag   = (int*)(wsb + 56662156);      //          4
  const size_t NEED = 56662160;
  if (ws_size < NEED) {
    hipMemsetAsync(d_out, 0x7F, (size_t)out_size * 2, stream);
    return;
  }

  k0_detect<<<1, 64, 0, stream>>>((const u16*)d_in[0], flag);
  hipMemsetAsync(wsum, 0, 2 * sizeof(float), stream);
  kt_transpose<<<dim3(4, 4, 2), 256, 0, stream>>>(flag, (const u16*)d_in[3], Wt);
  for (int m = 0; m < NM; ++m) {
    const int* src_m = src + (size_t)m * NE;
    const int* dst_m = dst + (size_t)m * NE;
    // CSR build
    hipMemsetAsync(rowptr, 0, (NND + 1) * sizeof(int), stream);
    kc_hist<<<NE / 256, 256, 0, stream>>>(dst_m, rowptr);
    kc_scan<<<1, 1024, 0, stream>>>(rowptr);
    hipMemcpyAsync(cursor, rowptr, NND * sizeof(int), hipMemcpyDeviceToDevice, stream);
    kc_scatter<<<NE / 256, 256, 0, stream>>>(src_m, dst_m, cursor, col);
    // GAT linear part
    k1_gemm<0><<<NND / 16, 256, 0, stream>>>(flag, d_in[0], d_in[3], d_in[4], d_in[5], feat, el, er, m);  // f32 fallback
    k1_mfma<<<dim3(391, 2), 256, 0, stream>>>(flag, (const u16*)d_in[0], Wt + (size_t)m * 65536, feat);
    k1b_elr<<<12500, 256, 0, stream>>>(flag, feat, (const u16*)d_in[4], (const u16*)d_in[5], el, er, m);
    // gather + softmax + elu
    if (m == 0) {
      k3_gather<0><<<12500, 256, 0, stream>>>(flag, 0, rowptr, col, el, er, feat, d_out);
      k3_gather<1><<<12500, 256, 0, stream>>>(flag, 1, rowptr, col, el, er, feat, d_out);
    } else {
      k3_gather<1><<<12500, 256, 0, stream>>>(flag, -1, rowptr, col, el, er, feat, z1);
    }
    k4_sem<0><<<NND / 8, 256, 0, stream>>>(flag, (m == 0) ? d_out : (void*)z1, d_in[6], d_in[7], d_in[8], wsum, m);
    k4_sem<1><<<NND / 8, 256, 0, stream>>>(flag, (m == 0) ? d_out : (void*)z1, d_in[6], d_in[7], d_in[8], wsum, m);
  }
  k5_out<0><<<(NND * HDIM / 4) / 256, 256, 0, stream>>>(flag, d_out, z1, wsum);
  k5_out<1><<<(NND * HDIM / 4) / 256, 256, 0, stream>>>(flag, d_out, z1, wsum);
}

// Round 5
// 818.209 us; speedup vs baseline: 1.8960x; 1.8960x over previous
//
#include <hip/hip_runtime.h>
#include <hip/hip_bf16.h>

#define NND 50000
#define NE 800000
#define NM 2
#define INF 256
#define NH 4
#define HDIM 256
#define SHID 128
#define SLOPE 0.2f

typedef unsigned short u16;
typedef __attribute__((ext_vector_type(8))) short bf16x8;
typedef __attribute__((ext_vector_type(4))) float f32x4;

__device__ __forceinline__ float us2f(u16 u) {
  union { unsigned int i; float f; } v; v.i = ((unsigned int)u) << 16; return v.f;
}
__device__ __forceinline__ u16 f2us(float f) {
  union { float f; unsigned int i; } v; v.f = f;
  unsigned int r = v.i + 0x7FFFu + ((v.i >> 16) & 1u);
  return (u16)(r >> 16);
}

#define GLDS(g, l) __builtin_amdgcn_global_load_lds( \
    (const __attribute__((address_space(1))) unsigned int*)(g), \
    (__attribute__((address_space(3))) unsigned int*)(l), 16, 0, 0)

// ---------------- convert h f32 -> bf16 ------------------------------------
__global__ __launch_bounds__(256) void kh_cvt(const float* __restrict__ h,
                                              u16* __restrict__ hb) {
  const size_t i = ((size_t)blockIdx.x * 256 + threadIdx.x) * 8;
  float4 a = *(const float4*)(h + i);
  float4 b = *(const float4*)(h + i + 4);
  bf16x8 r;
  r[0] = f2us(a.x); r[1] = f2us(a.y); r[2] = f2us(a.z); r[3] = f2us(a.w);
  r[4] = f2us(b.x); r[5] = f2us(b.y); r[6] = f2us(b.z); r[7] = f2us(b.w);
  *(bf16x8*)(hb + i) = r;
}

// ---------------- W transpose+convert: Wt[m][n][k] = W[m][k][n] ------------
__global__ __launch_bounds__(256) void kt_w(const float* __restrict__ W,
                                            u16* __restrict__ Wt) {
  __shared__ u16 tile[64][65];
  const int t = threadIdx.x;
  const int k0 = blockIdx.x * 64, n0 = blockIdx.y * 64;
  const float* Wm = W + (size_t)blockIdx.z * 65536;
  u16* Wtm = Wt + (size_t)blockIdx.z * 65536;
  const int lr = t >> 2, c0 = (t & 3) * 16;
#pragma unroll
  for (int i = 0; i < 16; ++i)
    tile[lr][c0 + i] = f2us(Wm[(size_t)(k0 + lr) * 256 + n0 + c0 + i]);
  __syncthreads();
#pragma unroll
  for (int i = 0; i < 16; ++i)
    Wtm[(size_t)(n0 + lr) * 256 + k0 + c0 + i] = tile[c0 + i][lr];
}

// w1 [256][128] f32 -> w1t [128][256] bf16
__global__ __launch_bounds__(256) void kt_w1(const float* __restrict__ w1,
                                             u16* __restrict__ w1t) {
  __shared__ u16 tile[64][65];
  const int t = threadIdx.x;
  const int k0 = blockIdx.x * 64, j0 = blockIdx.y * 64;
  const int lr = t >> 2, c0 = (t & 3) * 16;
#pragma unroll
  for (int i = 0; i < 16; ++i)
    tile[lr][c0 + i] = f2us(w1[(size_t)(k0 + lr) * SHID + j0 + c0 + i]);
  __syncthreads();
#pragma unroll
  for (int i = 0; i < 16; ++i)
    w1t[(size_t)(j0 + lr) * 256 + k0 + c0 + i] = tile[c0 + i][lr];
}

// ---------------- CSR build ------------------------------------------------
__global__ __launch_bounds__(256) void kc_hist(const int* __restrict__ dst,
                                               int* __restrict__ rowptr) {
  int e = blockIdx.x * 256 + threadIdx.x;
  if (e < NE) atomicAdd(rowptr + dst[e] + 1, 1);
}

__global__ __launch_bounds__(1024) void kc_scan(int* __restrict__ rowptr) {
  __shared__ int sums[1024];
  const int t = threadIdx.x;
  const int CH = 49;
  int lo = 1 + t * CH;
  int hi = lo + CH; if (hi > NND + 1) hi = NND + 1;
  int local = 0;
  for (int i = lo; i < hi; ++i) local += rowptr[i];
  sums[t] = local;
  __syncthreads();
  for (int s = 1; s < 1024; s <<= 1) {
    int v = (t >= s) ? sums[t - s] : 0;
    __syncthreads();
    sums[t] += v;
    __syncthreads();
  }
  int running = sums[t] - local;
  for (int i = lo; i < hi; ++i) {
    running += rowptr[i];
    rowptr[i] = running;
  }
}

__global__ __launch_bounds__(256) void kc_scatter(const int* __restrict__ src,
                                                  const int* __restrict__ dst,
                                                  int* __restrict__ cursor,
                                                  int* __restrict__ col) {
  int e = blockIdx.x * 256 + threadIdx.x;
  if (e >= NE) return;
  int pos = atomicAdd(cursor + dst[e], 1);
  col[pos] = src[e];
}

// ---------------- K1: feat = h @ W[m] via MFMA -----------------------------
// 128x128 tile, BK=32, 4 waves (2x2), each wave 64x64 = 4x4 16x16 fragments.
__global__ __launch_bounds__(256) void k1_mfma(
    const u16* __restrict__ hb, const u16* __restrict__ Wt,
    u16* __restrict__ feat)
{
  __shared__ u16 As[128 * 32];
  __shared__ u16 Bs[128 * 32];
  const int t = threadIdx.x;
  const int lane = t & 63;
  const int w = t >> 6;
  const int wr = w >> 1, wc = w & 1;
  const int row0 = blockIdx.x * 128;
  const int col0 = blockIdx.y * 128;

  const int sr = t >> 2;            // staging row (includes wave offset)
  const int skb = (t & 3) * 8;      // staging k element offset

  int ra0 = row0 + sr;       if (ra0 >= NND) ra0 = NND - 1;   // clamp (dupes ok)
  int ra1 = row0 + 64 + sr;  if (ra1 >= NND) ra1 = NND - 1;
  const int cb0 = col0 + sr, cb1 = col0 + 64 + sr;

  f32x4 acc[4][4];
#pragma unroll
  for (int i = 0; i < 4; ++i)
#pragma unroll
    for (int j = 0; j < 4; ++j) acc[i][j] = (f32x4){0.f, 0.f, 0.f, 0.f};

  for (int ks = 0; ks < 8; ++ks) {
    const int kb = ks * 32 + skb;
    __syncthreads();                       // previous iter's readers done
    GLDS(hb + (size_t)ra0 * INF + kb, As + w * 512);
    GLDS(hb + (size_t)ra1 * INF + kb, As + 2048 + w * 512);
    GLDS(Wt + (size_t)cb0 * 256 + kb, Bs + w * 512);
    GLDS(Wt + (size_t)cb1 * 256 + kb, Bs + 2048 + w * 512);
    __syncthreads();                       // drains vmcnt before barrier
    bf16x8 af[4], bfr[4];
#pragma unroll
    for (int mi = 0; mi < 4; ++mi)
      af[mi] = *(const bf16x8*)(As + (wr * 64 + mi * 16 + (lane & 15)) * 32 + (lane >> 4) * 8);
#pragma unroll
    for (int ni = 0; ni < 4; ++ni)
      bfr[ni] = *(const bf16x8*)(Bs + (wc * 64 + ni * 16 + (lane & 15)) * 32 + (lane >> 4) * 8);
#pragma unroll
    for (int mi = 0; mi < 4; ++mi)
#pragma unroll
      for (int ni = 0; ni < 4; ++ni)
        acc[mi][ni] = __builtin_amdgcn_mfma_f32_16x16x32_bf16(af[mi], bfr[ni], acc[mi][ni], 0, 0, 0);
  }
  // epilogue: C layout col=lane&15, row=(lane>>4)*4+i  [m89/m91]
#pragma unroll
  for (int mi = 0; mi < 4; ++mi) {
    const int r_base = row0 + wr * 64 + mi * 16 + (lane >> 4) * 4;
#pragma unroll
    for (int i = 0; i < 4; ++i) {
      const int r = r_base + i;
      if (r < NND) {
#pragma unroll
        for (int ni = 0; ni < 4; ++ni) {
          const int c = col0 + wc * 64 + ni * 16 + (lane & 15);
          feat[(size_t)r * HDIM + c] = f2us(acc[mi][ni][i]);
        }
      }
    }
  }
}

// ---------------- K1b: el/er from feat (al/ar are f32) ---------------------
__global__ __launch_bounds__(256) void k1b_elr(
    const u16* __restrict__ feat,
    const float* __restrict__ al, const float* __restrict__ ar,
    float* __restrict__ el, float* __restrict__ er)
{
  const int n = blockIdx.x * 4 + (threadIdx.x >> 6);
  const int lane = threadIdx.x & 63;
  ushort4 f4 = *(const ushort4*)(feat + (size_t)n * HDIM + lane * 4);
  float4 a4 = *(const float4*)(al + lane * 4);
  float4 r4 = *(const float4*)(ar + lane * 4);
  float fl = us2f(f4.x) * a4.x + us2f(f4.y) * a4.y
           + us2f(f4.z) * a4.z + us2f(f4.w) * a4.w;
  float fr = us2f(f4.x) * r4.x + us2f(f4.y) * r4.y
           + us2f(f4.z) * r4.z + us2f(f4.w) * r4.w;
#pragma unroll
  for (int o = 1; o < 16; o <<= 1) {
    fl += __shfl_xor(fl, o, 64);
    fr += __shfl_xor(fr, o, 64);
  }
  if ((lane & 15) == 0) {
    el[n * 4 + (lane >> 4)] = fl;
    er[n * 4 + (lane >> 4)] = fr;
  }
}

// ---------------- K3: CSR gather (den + aggregate + elu + z store) ---------
// One wave per dst node; lane covers 4 contiguous feats (head = lane>>4).
template<int OBF>
__global__ __launch_bounds__(256) void k3_gather(
    const int* __restrict__ rowptr, const int* __restrict__ col,
    const float* __restrict__ el, const float* __restrict__ er,
    const u16* __restrict__ feat, void* __restrict__ z)
{
  const int d = blockIdx.x * 4 + (threadIdx.x >> 6);
  if (d >= NND) return;
  const int lane = threadIdx.x & 63;
  const int h = lane >> 4;
  const int beg = rowptr[d], end = rowptr[d + 1];
  const float erh = er[d * 4 + h];
  float den = 0.f;
  for (int j = beg; j < end; ++j) {
    int s = col[j];
    float x = el[s * 4 + h] + erh;
    x = x > 0.f ? x : SLOPE * x;
    den += expf(x);
  }
  const float inv = 1.f / fmaxf(den, 1e-9f);
  float a0 = 0.f, a1 = 0.f, a2 = 0.f, a3 = 0.f;
  for (int j = beg; j < end; ++j) {
    int s = col[j];
    float x = el[s * 4 + h] + erh;
    x = x > 0.f ? x : SLOPE * x;
    float alpha = expf(x) * inv;
    const ushort4 f4 = *(const ushort4*)(feat + (size_t)s * HDIM + lane * 4);
    a0 = fmaf(alpha, us2f(f4.x), a0);
    a1 = fmaf(alpha, us2f(f4.y), a1);
    a2 = fmaf(alpha, us2f(f4.z), a2);
    a3 = fmaf(alpha, us2f(f4.w), a3);
  }
  a0 = a0 > 0.f ? a0 : expf(a0) - 1.f;
  a1 = a1 > 0.f ? a1 : expf(a1) - 1.f;
  a2 = a2 > 0.f ? a2 : expf(a2) - 1.f;
  a3 = a3 > 0.f ? a3 : expf(a3) - 1.f;
  const size_t idx = (size_t)d * HDIM + lane * 4;
  if (OBF) {
    ushort4 r; r.x = f2us(a0); r.y = f2us(a1); r.z = f2us(a2); r.w = f2us(a3);
    *(ushort4*)((u16*)z + idx) = r;
  } else {
    float4 r; r.x = a0; r.y = a1; r.z = a2; r.w = a3;
    *(float4*)((float*)z + idx) = r;
  }
}

// ---------------- K4: wsum[m] += sum tanh(z@w1+b1)*w2 via MFMA -------------
// 128 rows x 128 cols (all SHID), BK=32; ZBF: 1 = z bf16, 0 = z f32 (d_out).
template<int ZBF>
__global__ __launch_bounds__(256) void k4_mfma(
    const void* __restrict__ zsrc, const u16* __restrict__ w1t,
    const float* __restrict__ b1, const float* __restrict__ w2,
    float* __restrict__ wsum, int midx)
{
  __shared__ u16 As[128 * 32];
  __shared__ u16 Bs[128 * 32];
  __shared__ float red[4];
  const int t = threadIdx.x;
  const int lane = t & 63;
  const int w = t >> 6;
  const int wr = w >> 1, wc = w & 1;
  const int row0 = blockIdx.x * 128;
  const int sr = t >> 2;
  const int skb = (t & 3) * 8;
  int ra0 = row0 + sr;       if (ra0 >= NND) ra0 = NND - 1;
  int ra1 = row0 + 64 + sr;  if (ra1 >= NND) ra1 = NND - 1;
  const int cb0 = sr, cb1 = 64 + sr;        // w1t rows 0..127

  f32x4 acc[4][4];
#pragma unroll
  for (int i = 0; i < 4; ++i)
#pragma unroll
    for (int j = 0; j < 4; ++j) acc[i][j] = (f32x4){0.f, 0.f, 0.f, 0.f};

  for (int ks = 0; ks < 8; ++ks) {
    const int kb = ks * 32 + skb;
    __syncthreads();
    if (ZBF) {
      GLDS((const u16*)zsrc + (size_t)ra0 * HDIM + kb, As + w * 512);
      GLDS((const u16*)zsrc + (size_t)ra1 * HDIM + kb, As + 2048 + w * 512);
    } else {
      const float* zf = (const float*)zsrc;
      float4 a = *(const float4*)(zf + (size_t)ra0 * HDIM + kb);
      float4 b = *(const float4*)(zf + (size_t)ra0 * HDIM + kb + 4);
      bf16x8 r;
      r[0] = f2us(a.x); r[1] = f2us(a.y); r[2] = f2us(a.z); r[3] = f2us(a.w);
      r[4] = f2us(b.x); r[5] = f2us(b.y); r[6] = f2us(b.z); r[7] = f2us(b.w);
      *(bf16x8*)(As + sr * 32 + skb) = r;
      a = *(const float4*)(zf + (size_t)ra1 * HDIM + kb);
      b = *(const float4*)(zf + (size_t)ra1 * HDIM + kb + 4);
      r[0] = f2us(a.x); r[1] = f2us(a.y); r[2] = f2us(a.z); r[3] = f2us(a.w);
      r[4] = f2us(b.x); r[5] = f2us(b.y); r[6] = f2us(b.z); r[7] = f2us(b.w);
      *(bf16x8*)(As + (64 + sr) * 32 + skb) = r;
    }
    GLDS(w1t + (size_t)cb0 * 256 + kb, Bs + w * 512);
    GLDS(w1t + (size_t)cb1 * 256 + kb, Bs + 2048 + w * 512);
    __syncthreads();
    bf16x8 af[4], bfr[4];
#pragma unroll
    for (int mi = 0; mi < 4; ++mi)
      af[mi] = *(const bf16x8*)(As + (wr * 64 + mi * 16 + (lane & 15)) * 32 + (lane >> 4) * 8);
#pragma unroll
    for (int ni = 0; ni < 4; ++ni)
      bfr[ni] = *(const bf16x8*)(Bs + (wc * 64 + ni * 16 + (lane & 15)) * 32 + (lane >> 4) * 8);
#pragma unroll
    for (int mi = 0; mi < 4; ++mi)
#pragma unroll
      for (int ni = 0; ni < 4; ++ni)
        acc[mi][ni] = __builtin_amdgcn_mfma_f32_16x16x32_bf16(af[mi], bfr[ni], acc[mi][ni], 0, 0, 0);
  }
  // epilogue: sum tanh(s + b1[c]) * w2[c] over valid rows
  float sum = 0.f;
#pragma unroll
  for (int ni = 0; ni < 4; ++ni) {
    const int c = wc * 64 + ni * 16 + (lane & 15);
    const float b1c = b1[c], w2c = w2[c];
#pragma unroll
    for (int mi = 0; mi < 4; ++mi) {
      const int r_base = row0 + wr * 64 + mi * 16 + (lane >> 4) * 4;
#pragma unroll
      for (int i = 0; i < 4; ++i) {
        if (r_base + i < NND)
          sum += tanhf(acc[mi][ni][i] + b1c) * w2c;
      }
    }
  }
#pragma unroll
  for (int o = 32; o; o >>= 1) sum += __shfl_xor(sum, o, 64);
  if (lane == 0) red[w] = sum;
  __syncthreads();
  if (t == 0) unsafeAtomicAdd(wsum + midx, red[0] + red[1] + red[2] + red[3]);
}

// ---------------- K5: beta=softmax(wsum/N); out = b0*z0 + b1*z1 ------------
__global__ __launch_bounds__(256) void k5_out(
    float* __restrict__ out, const u16* __restrict__ z1,
    const float* __restrict__ wsum)
{
  const int i = blockIdx.x * 256 + threadIdx.x;
  float w0 = wsum[0] * (1.0f / NND);
  float w1v = wsum[1] * (1.0f / NND);
  float mx = fmaxf(w0, w1v);
  float e0 = expf(w0 - mx), e1 = expf(w1v - mx);
  float inv = 1.f / (e0 + e1);
  float b0 = e0 * inv, b1 = e1 * inv;
  float4 a = ((const float4*)out)[i];
  ushort4 zb = ((const ushort4*)z1)[i];
  float4 r;
  r.x = b0 * a.x + b1 * us2f(zb.x);
  r.y = b0 * a.y + b1 * us2f(zb.y);
  r.z = b0 * a.z + b1 * us2f(zb.z);
  r.w = b0 * a.w + b1 * us2f(zb.w);
  ((float4*)out)[i] = r;
}

extern "C" void kernel_launch(void* const* d_in, const int* in_sizes, int n_in,
                              void* d_out, int out_size, void* d_ws, size_t ws_size,
                              hipStream_t stream)
{
  const float* h  = (const float*)d_in[0];
  const int* src  = (const int*)d_in[1];
  const int* dst  = (const int*)d_in[2];
  const float* W  = (const float*)d_in[3];
  const float* al = (const float*)d_in[4];
  const float* ar = (const float*)d_in[5];
  const float* w1 = (const float*)d_in[6];
  const float* b1 = (const float*)d_in[7];
  const float* w2 = (const float*)d_in[8];

  // workspace layout (bytes)
  char* wsb = (char*)d_ws;
  u16*   feat   = (u16*)(wsb);                 // 25,600,000
  u16*   hz     = (u16*)(wsb + 25600000);      // 25,600,000  (bf16 h; z1 aliases)
  int*   col    = (int*)(wsb + 51200000);      //  3,200,000
  u16*   Wt     = (u16*)(wsb + 54400000);      //    262,144
  u16*   w1t    = (u16*)(wsb + 54662144);      //     65,536
  float* el     = (float*)(wsb + 54727680);    //    800,000
  float* er     = (float*)(wsb + 55527680);    //    800,000
  int*   rowptr = (int*)(wsb + 56327680);      //    200,004
  int*   cursor = (int*)(wsb + 56527684);      //    200,000
  float* wsum   = (float*)(wsb + 56727684);    //          8
  const size_t NEED = 56727692;
  if (ws_size < NEED) {
    hipMemsetAsync(d_out, 0x7F, (size_t)out_size * 4, stream);
    return;
  }
  u16* z1 = hz;        // alias: hz dead after k1_mfma(m=1), z1 written by k3(m=1)
  float* outp = (float*)d_out;

  kh_cvt<<<6250, 256, 0, stream>>>(h, hz);
  kt_w<<<dim3(4, 4, 2), 256, 0, stream>>>(W, Wt);
  kt_w1<<<dim3(4, 2), 256, 0, stream>>>(w1, w1t);
  hipMemsetAsync(wsum, 0, 2 * sizeof(float), stream);
  for (int m = 0; m < NM; ++m) {
    const int* src_m = src + (size_t)m * NE;
    const int* dst_m = dst + (size_t)m * NE;
    hipMemsetAsync(rowptr, 0, (NND + 1) * sizeof(int), stream);
    kc_hist<<<NE / 256, 256, 0, stream>>>(dst_m, rowptr);
    kc_scan<<<1, 1024, 0, stream>>>(rowptr);
    hipMemcpyAsync(cursor, rowptr, NND * sizeof(int), hipMemcpyDeviceToDevice, stream);
    kc_scatter<<<NE / 256, 256, 0, stream>>>(src_m, dst_m, cursor, col);
    k1_mfma<<<dim3(391, 2), 256, 0, stream>>>(hz, Wt + (size_t)m * 65536, feat);
    k1b_elr<<<12500, 256, 0, stream>>>(feat, al + (size_t)m * HDIM, ar + (size_t)m * HDIM, el, er);
    if (m == 0) {
      k3_gather<0><<<12500, 256, 0, stream>>>(rowptr, col, el, er, feat, d_out);
      k4_mfma<0><<<391, 256, 0, stream>>>(d_out, w1t, b1, w2, wsum, 0);
    } else {
      k3_gather<1><<<12500, 256, 0, stream>>>(rowptr, col, el, er, feat, z1);
      k4_mfma<1><<<391, 256, 0, stream>>>(z1, w1t, b1, w2, wsum, 1);
    }
  }
  k5_out<<<(NND * HDIM / 4) / 256, 256, 0, stream>>>(outp, z1, wsum);
}

// Round 6
// 583.379 us; speedup vs baseline: 2.6592x; 1.4025x over previous
//
#include <hip/hip_runtime.h>
#include <hip/hip_bf16.h>

#define NND 50000
#define NE 800000
#define NM 2
#define INF 256
#define NH 4
#define HDIM 256
#define SHID 128
#define SLOPE 0.2f

typedef unsigned short u16;
typedef __attribute__((ext_vector_type(8))) short bf16x8;
typedef __attribute__((ext_vector_type(4))) float f32x4;

__device__ __forceinline__ float us2f(u16 u) {
  union { unsigned int i; float f; } v; v.i = ((unsigned int)u) << 16; return v.f;
}
__device__ __forceinline__ u16 f2us(float f) {
  union { float f; unsigned int i; } v; v.f = f;
  unsigned int r = v.i + 0x7FFFu + ((v.i >> 16) & 1u);
  return (u16)(r >> 16);
}

#define GLDS(g, l) __builtin_amdgcn_global_load_lds( \
    (const __attribute__((address_space(1))) unsigned int*)(g), \
    (__attribute__((address_space(3))) unsigned int*)(l), 16, 0, 0)

// ---------------- convert h f32 -> bf16 ------------------------------------
__global__ __launch_bounds__(256) void kh_cvt(const float* __restrict__ h,
                                              u16* __restrict__ hb) {
  const size_t i = ((size_t)blockIdx.x * 256 + threadIdx.x) * 8;
  float4 a = *(const float4*)(h + i);
  float4 b = *(const float4*)(h + i + 4);
  bf16x8 r;
  r[0] = f2us(a.x); r[1] = f2us(a.y); r[2] = f2us(a.z); r[3] = f2us(a.w);
  r[4] = f2us(b.x); r[5] = f2us(b.y); r[6] = f2us(b.z); r[7] = f2us(b.w);
  *(bf16x8*)(hb + i) = r;
}

// ---------------- W transpose+convert: Wt[m][n][k] = W[m][k][n] ------------
__global__ __launch_bounds__(256) void kt_w(const float* __restrict__ W,
                                            u16* __restrict__ Wt) {
  __shared__ u16 tile[64][65];
  const int t = threadIdx.x;
  const int k0 = blockIdx.x * 64, n0 = blockIdx.y * 64;
  const float* Wm = W + (size_t)blockIdx.z * 65536;
  u16* Wtm = Wt + (size_t)blockIdx.z * 65536;
  const int lr = t >> 2, c0 = (t & 3) * 16;
#pragma unroll
  for (int i = 0; i < 16; ++i)
    tile[lr][c0 + i] = f2us(Wm[(size_t)(k0 + lr) * 256 + n0 + c0 + i]);
  __syncthreads();
#pragma unroll
  for (int i = 0; i < 16; ++i)
    Wtm[(size_t)(n0 + lr) * 256 + k0 + c0 + i] = tile[c0 + i][lr];
}

// w1 [256][128] f32 -> w1t [128][256] bf16
__global__ __launch_bounds__(256) void kt_w1(const float* __restrict__ w1,
                                             u16* __restrict__ w1t) {
  __shared__ u16 tile[64][65];
  const int t = threadIdx.x;
  const int k0 = blockIdx.x * 64, j0 = blockIdx.y * 64;
  const int lr = t >> 2, c0 = (t & 3) * 16;
#pragma unroll
  for (int i = 0; i < 16; ++i)
    tile[lr][c0 + i] = f2us(w1[(size_t)(k0 + lr) * SHID + j0 + c0 + i]);
  __syncthreads();
#pragma unroll
  for (int i = 0; i < 16; ++i)
    w1t[(size_t)(j0 + lr) * 256 + k0 + c0 + i] = tile[c0 + i][lr];
}

// ---------------- CSR build ------------------------------------------------
__global__ __launch_bounds__(256) void kc_hist(const int* __restrict__ dst,
                                               int* __restrict__ rowptr) {
  int e = blockIdx.x * 256 + threadIdx.x;
  if (e < NE) atomicAdd(rowptr + dst[e] + 1, 1);
}

__global__ __launch_bounds__(1024) void kc_scan(int* __restrict__ rowptr) {
  __shared__ int sums[1024];
  const int t = threadIdx.x;
  const int CH = 49;
  int lo = 1 + t * CH;
  int hi = lo + CH; if (hi > NND + 1) hi = NND + 1;
  int local = 0;
  for (int i = lo; i < hi; ++i) local += rowptr[i];
  sums[t] = local;
  __syncthreads();
  for (int s = 1; s < 1024; s <<= 1) {
    int v = (t >= s) ? sums[t - s] : 0;
    __syncthreads();
    sums[t] += v;
    __syncthreads();
  }
  int running = sums[t] - local;
  for (int i = lo; i < hi; ++i) {
    running += rowptr[i];
    rowptr[i] = running;
  }
}

// scatter + per-edge attention exp for all 4 heads (CSR order)
__global__ __launch_bounds__(256) void kc_scatter(
    const int* __restrict__ src, const int* __restrict__ dst,
    int* __restrict__ cursor, int* __restrict__ col,
    const float* __restrict__ el, const float* __restrict__ er,
    float* __restrict__ exps)
{
  int e = blockIdx.x * 256 + threadIdx.x;
  if (e >= NE) return;
  int s = src[e], d = dst[e];
  int pos = atomicAdd(cursor + d, 1);
  col[pos] = s;
  float4 a = *(const float4*)(el + s * 4);
  float4 b = *(const float4*)(er + d * 4);
  float4 r;
  float x;
  x = a.x + b.x; x = x > 0.f ? x : SLOPE * x; r.x = __expf(x);
  x = a.y + b.y; x = x > 0.f ? x : SLOPE * x; r.y = __expf(x);
  x = a.z + b.z; x = x > 0.f ? x : SLOPE * x; r.z = __expf(x);
  x = a.w + b.w; x = x > 0.f ? x : SLOPE * x; r.w = __expf(x);
  *(float4*)(exps + (size_t)pos * 4) = r;
}

// ---------------- K1: feat = h @ W[m] via MFMA -----------------------------
// 128x128 tile, BK=32, 4 waves (2x2), each wave 64x64 = 4x4 16x16 fragments.
__global__ __launch_bounds__(256) void k1_mfma(
    const u16* __restrict__ hb, const u16* __restrict__ Wt,
    u16* __restrict__ feat)
{
  __shared__ u16 As[128 * 32];
  __shared__ u16 Bs[128 * 32];
  const int t = threadIdx.x;
  const int lane = t & 63;
  const int w = t >> 6;
  const int wr = w >> 1, wc = w & 1;
  const int row0 = blockIdx.x * 128;
  const int col0 = blockIdx.y * 128;

  const int sr = t >> 2;            // staging row (includes wave offset)
  const int skb = (t & 3) * 8;      // staging k element offset

  int ra0 = row0 + sr;       if (ra0 >= NND) ra0 = NND - 1;   // clamp (dupes ok)
  int ra1 = row0 + 64 + sr;  if (ra1 >= NND) ra1 = NND - 1;
  const int cb0 = col0 + sr, cb1 = col0 + 64 + sr;

  f32x4 acc[4][4];
#pragma unroll
  for (int i = 0; i < 4; ++i)
#pragma unroll
    for (int j = 0; j < 4; ++j) acc[i][j] = (f32x4){0.f, 0.f, 0.f, 0.f};

  for (int ks = 0; ks < 8; ++ks) {
    const int kb = ks * 32 + skb;
    __syncthreads();                       // previous iter's readers done
    GLDS(hb + (size_t)ra0 * INF + kb, As + w * 512);
    GLDS(hb + (size_t)ra1 * INF + kb, As + 2048 + w * 512);
    GLDS(Wt + (size_t)cb0 * 256 + kb, Bs + w * 512);
    GLDS(Wt + (size_t)cb1 * 256 + kb, Bs + 2048 + w * 512);
    __syncthreads();                       // drains vmcnt before barrier
    bf16x8 af[4], bfr[4];
#pragma unroll
    for (int mi = 0; mi < 4; ++mi)
      af[mi] = *(const bf16x8*)(As + (wr * 64 + mi * 16 + (lane & 15)) * 32 + (lane >> 4) * 8);
#pragma unroll
    for (int ni = 0; ni < 4; ++ni)
      bfr[ni] = *(const bf16x8*)(Bs + (wc * 64 + ni * 16 + (lane & 15)) * 32 + (lane >> 4) * 8);
#pragma unroll
    for (int mi = 0; mi < 4; ++mi)
#pragma unroll
      for (int ni = 0; ni < 4; ++ni)
        acc[mi][ni] = __builtin_amdgcn_mfma_f32_16x16x32_bf16(af[mi], bfr[ni], acc[mi][ni], 0, 0, 0);
  }
  // epilogue: C layout col=lane&15, row=(lane>>4)*4+i  [m89/m91]
#pragma unroll
  for (int mi = 0; mi < 4; ++mi) {
    const int r_base = row0 + wr * 64 + mi * 16 + (lane >> 4) * 4;
#pragma unroll
    for (int i = 0; i < 4; ++i) {
      const int r = r_base + i;
      if (r < NND) {
#pragma unroll
        for (int ni = 0; ni < 4; ++ni) {
          const int c = col0 + wc * 64 + ni * 16 + (lane & 15);
          feat[(size_t)r * HDIM + c] = f2us(acc[mi][ni][i]);
        }
      }
    }
  }
}

// ---------------- K1b: el/er from feat (al/ar are f32) ---------------------
__global__ __launch_bounds__(256) void k1b_elr(
    const u16* __restrict__ feat,
    const float* __restrict__ al, const float* __restrict__ ar,
    float* __restrict__ el, float* __restrict__ er)
{
  const int n = blockIdx.x * 4 + (threadIdx.x >> 6);
  const int lane = threadIdx.x & 63;
  ushort4 f4 = *(const ushort4*)(feat + (size_t)n * HDIM + lane * 4);
  float4 a4 = *(const float4*)(al + lane * 4);
  float4 r4 = *(const float4*)(ar + lane * 4);
  float fl = us2f(f4.x) * a4.x + us2f(f4.y) * a4.y
           + us2f(f4.z) * a4.z + us2f(f4.w) * a4.w;
  float fr = us2f(f4.x) * r4.x + us2f(f4.y) * r4.y
           + us2f(f4.z) * r4.z + us2f(f4.w) * r4.w;
#pragma unroll
  for (int o = 1; o < 16; o <<= 1) {
    fl += __shfl_xor(fl, o, 64);
    fr += __shfl_xor(fr, o, 64);
  }
  if ((lane & 15) == 0) {
    el[n * 4 + (lane >> 4)] = fl;
    er[n * 4 + (lane >> 4)] = fr;
  }
}

// ---------------- K3: CSR gather (den + aggregate + elu + z store) ---------
// One wave per dst node; lane covers 4 contiguous feats (head = lane>>4).
// den: lane (lane&15) strides edges by 16, shfl-reduce within head group.
// agg: unroll x4 so 4 feat-row gathers are in flight per wave.
template<int OBF>
__global__ __launch_bounds__(256) void k3_gather(
    const int* __restrict__ rowptr, const int* __restrict__ col,
    const float* __restrict__ exps,
    const u16* __restrict__ feat, void* __restrict__ z)
{
  const int d = blockIdx.x * 4 + (threadIdx.x >> 6);
  if (d >= NND) return;
  const int lane = threadIdx.x & 63;
  const int h = lane >> 4;
  const int sub = lane & 15;
  const int beg = rowptr[d], end = rowptr[d + 1];

  float den = 0.f;
  for (int j = beg + sub; j < end; j += 16)
    den += exps[(size_t)j * 4 + h];
#pragma unroll
  for (int o = 1; o < 16; o <<= 1) den += __shfl_xor(den, o, 64);
  const float inv = 1.f / fmaxf(den, 1e-9f);

  float a0 = 0.f, a1 = 0.f, a2 = 0.f, a3 = 0.f;
  int j = beg;
  for (; j + 3 < end; j += 4) {
    int s0 = col[j], s1 = col[j + 1], s2 = col[j + 2], s3 = col[j + 3];
    float p0 = exps[(size_t)j * 4 + h] * inv;
    float p1 = exps[(size_t)(j + 1) * 4 + h] * inv;
    float p2 = exps[(size_t)(j + 2) * 4 + h] * inv;
    float p3 = exps[(size_t)(j + 3) * 4 + h] * inv;
    const ushort4 f0 = *(const ushort4*)(feat + (size_t)s0 * HDIM + lane * 4);
    const ushort4 f1 = *(const ushort4*)(feat + (size_t)s1 * HDIM + lane * 4);
    const ushort4 f2 = *(const ushort4*)(feat + (size_t)s2 * HDIM + lane * 4);
    const ushort4 f3 = *(const ushort4*)(feat + (size_t)s3 * HDIM + lane * 4);
    a0 = fmaf(p0, us2f(f0.x), a0); a1 = fmaf(p0, us2f(f0.y), a1);
    a2 = fmaf(p0, us2f(f0.z), a2); a3 = fmaf(p0, us2f(f0.w), a3);
    a0 = fmaf(p1, us2f(f1.x), a0); a1 = fmaf(p1, us2f(f1.y), a1);
    a2 = fmaf(p1, us2f(f1.z), a2); a3 = fmaf(p1, us2f(f1.w), a3);
    a0 = fmaf(p2, us2f(f2.x), a0); a1 = fmaf(p2, us2f(f2.y), a1);
    a2 = fmaf(p2, us2f(f2.z), a2); a3 = fmaf(p2, us2f(f2.w), a3);
    a0 = fmaf(p3, us2f(f3.x), a0); a1 = fmaf(p3, us2f(f3.y), a1);
    a2 = fmaf(p3, us2f(f3.z), a2); a3 = fmaf(p3, us2f(f3.w), a3);
  }
  for (; j < end; ++j) {
    int s = col[j];
    float p = exps[(size_t)j * 4 + h] * inv;
    const ushort4 f4 = *(const ushort4*)(feat + (size_t)s * HDIM + lane * 4);
    a0 = fmaf(p, us2f(f4.x), a0); a1 = fmaf(p, us2f(f4.y), a1);
    a2 = fmaf(p, us2f(f4.z), a2); a3 = fmaf(p, us2f(f4.w), a3);
  }
  a0 = a0 > 0.f ? a0 : expf(a0) - 1.f;
  a1 = a1 > 0.f ? a1 : expf(a1) - 1.f;
  a2 = a2 > 0.f ? a2 : expf(a2) - 1.f;
  a3 = a3 > 0.f ? a3 : expf(a3) - 1.f;
  const size_t idx = (size_t)d * HDIM + lane * 4;
  if (OBF) {
    ushort4 r; r.x = f2us(a0); r.y = f2us(a1); r.z = f2us(a2); r.w = f2us(a3);
    *(ushort4*)((u16*)z + idx) = r;
  } else {
    float4 r; r.x = a0; r.y = a1; r.z = a2; r.w = a3;
    *(float4*)((float*)z + idx) = r;
  }
}

// ---------------- K4: wsum[m] += sum tanh(z@w1+b1)*w2 via MFMA -------------
template<int ZBF>
__global__ __launch_bounds__(256) void k4_mfma(
    const void* __restrict__ zsrc, const u16* __restrict__ w1t,
    const float* __restrict__ b1, const float* __restrict__ w2,
    float* __restrict__ wsum, int midx)
{
  __shared__ u16 As[128 * 32];
  __shared__ u16 Bs[128 * 32];
  __shared__ float red[4];
  const int t = threadIdx.x;
  const int lane = t & 63;
  const int w = t >> 6;
  const int wr = w >> 1, wc = w & 1;
  const int row0 = blockIdx.x * 128;
  const int sr = t >> 2;
  const int skb = (t & 3) * 8;
  int ra0 = row0 + sr;       if (ra0 >= NND) ra0 = NND - 1;
  int ra1 = row0 + 64 + sr;  if (ra1 >= NND) ra1 = NND - 1;
  const int cb0 = sr, cb1 = 64 + sr;

  f32x4 acc[4][4];
#pragma unroll
  for (int i = 0; i < 4; ++i)
#pragma unroll
    for (int j = 0; j < 4; ++j) acc[i][j] = (f32x4){0.f, 0.f, 0.f, 0.f};

  for (int ks = 0; ks < 8; ++ks) {
    const int kb = ks * 32 + skb;
    __syncthreads();
    if (ZBF) {
      GLDS((const u16*)zsrc + (size_t)ra0 * HDIM + kb, As + w * 512);
      GLDS((const u16*)zsrc + (size_t)ra1 * HDIM + kb, As + 2048 + w * 512);
    } else {
      const float* zf = (const float*)zsrc;
      float4 a = *(const float4*)(zf + (size_t)ra0 * HDIM + kb);
      float4 b = *(const float4*)(zf + (size_t)ra0 * HDIM + kb + 4);
      bf16x8 r;
      r[0] = f2us(a.x); r[1] = f2us(a.y); r[2] = f2us(a.z); r[3] = f2us(a.w);
      r[4] = f2us(b.x); r[5] = f2us(b.y); r[6] = f2us(b.z); r[7] = f2us(b.w);
      *(bf16x8*)(As + sr * 32 + skb) = r;
      a = *(const float4*)(zf + (size_t)ra1 * HDIM + kb);
      b = *(const float4*)(zf + (size_t)ra1 * HDIM + kb + 4);
      r[0] = f2us(a.x); r[1] = f2us(a.y); r[2] = f2us(a.z); r[3] = f2us(a.w);
      r[4] = f2us(b.x); r[5] = f2us(b.y); r[6] = f2us(b.z); r[7] = f2us(b.w);
      *(bf16x8*)(As + (64 + sr) * 32 + skb) = r;
    }
    GLDS(w1t + (size_t)cb0 * 256 + kb, Bs + w * 512);
    GLDS(w1t + (size_t)cb1 * 256 + kb, Bs + 2048 + w * 512);
    __syncthreads();
    bf16x8 af[4], bfr[4];
#pragma unroll
    for (int mi = 0; mi < 4; ++mi)
      af[mi] = *(const bf16x8*)(As + (wr * 64 + mi * 16 + (lane & 15)) * 32 + (lane >> 4) * 8);
#pragma unroll
    for (int ni = 0; ni < 4; ++ni)
      bfr[ni] = *(const bf16x8*)(Bs + (wc * 64 + ni * 16 + (lane & 15)) * 32 + (lane >> 4) * 8);
#pragma unroll
    for (int mi = 0; mi < 4; ++mi)
#pragma unroll
      for (int ni = 0; ni < 4; ++ni)
        acc[mi][ni] = __builtin_amdgcn_mfma_f32_16x16x32_bf16(af[mi], bfr[ni], acc[mi][ni], 0, 0, 0);
  }
  float sum = 0.f;
#pragma unroll
  for (int ni = 0; ni < 4; ++ni) {
    const int c = wc * 64 + ni * 16 + (lane & 15);
    const float b1c = b1[c], w2c = w2[c];
#pragma unroll
    for (int mi = 0; mi < 4; ++mi) {
      const int r_base = row0 + wr * 64 + mi * 16 + (lane >> 4) * 4;
#pragma unroll
      for (int i = 0; i < 4; ++i) {
        if (r_base + i < NND)
          sum += tanhf(acc[mi][ni][i] + b1c) * w2c;
      }
    }
  }
#pragma unroll
  for (int o = 32; o; o >>= 1) sum += __shfl_xor(sum, o, 64);
  if (lane == 0) red[w] = sum;
  __syncthreads();
  if (t == 0) unsafeAtomicAdd(wsum + midx, red[0] + red[1] + red[2] + red[3]);
}

// ---------------- K5: beta=softmax(wsum/N); out = b0*z0 + b1*z1 ------------
__global__ __launch_bounds__(256) void k5_out(
    float* __restrict__ out, const u16* __restrict__ z1,
    const float* __restrict__ wsum)
{
  const int i = blockIdx.x * 256 + threadIdx.x;
  float w0 = wsum[0] * (1.0f / NND);
  float w1v = wsum[1] * (1.0f / NND);
  float mx = fmaxf(w0, w1v);
  float e0 = expf(w0 - mx), e1 = expf(w1v - mx);
  float inv = 1.f / (e0 + e1);
  float b0 = e0 * inv, b1 = e1 * inv;
  float4 a = ((const float4*)out)[i];
  ushort4 zb = ((const ushort4*)z1)[i];
  float4 r;
  r.x = b0 * a.x + b1 * us2f(zb.x);
  r.y = b0 * a.y + b1 * us2f(zb.y);
  r.z = b0 * a.z + b1 * us2f(zb.z);
  r.w = b0 * a.w + b1 * us2f(zb.w);
  ((float4*)out)[i] = r;
}

extern "C" void kernel_launch(void* const* d_in, const int* in_sizes, int n_in,
                              void* d_out, int out_size, void* d_ws, size_t ws_size,
                              hipStream_t stream)
{
  const float* h  = (const float*)d_in[0];
  const int* src  = (const int*)d_in[1];
  const int* dst  = (const int*)d_in[2];
  const float* W  = (const float*)d_in[3];
  const float* al = (const float*)d_in[4];
  const float* ar = (const float*)d_in[5];
  const float* w1 = (const float*)d_in[6];
  const float* b1 = (const float*)d_in[7];
  const float* w2 = (const float*)d_in[8];

  // workspace layout (bytes)
  char* wsb = (char*)d_ws;
  u16*   feat   = (u16*)(wsb);                 // 25,600,000
  u16*   hz     = (u16*)(wsb + 25600000);      // 25,600,000  (bf16 h; z1 aliases)
  float* exps   = (float*)(wsb + 51200000);    // 12,800,000
  int*   col    = (int*)(wsb + 64000000);      //  3,200,000
  u16*   Wt     = (u16*)(wsb + 67200000);      //    262,144
  u16*   w1t    = (u16*)(wsb + 67462144);      //     65,536
  float* el     = (float*)(wsb + 67527680);    //    800,000
  float* er     = (float*)(wsb + 68327680);    //    800,000
  int*   rowptr = (int*)(wsb + 69127680);      //    200,004
  int*   cursor = (int*)(wsb + 69327684);      //    200,000
  float* wsum   = (float*)(wsb + 69527684);    //          8
  const size_t NEED = 69527692;
  if (ws_size < NEED) {
    hipMemsetAsync(d_out, 0x7F, (size_t)out_size * 4, stream);
    return;
  }
  u16* z1 = hz;        // alias: hz dead after k1_mfma(m=1), z1 written by k3(m=1)
  float* outp = (float*)d_out;

  kh_cvt<<<6250, 256, 0, stream>>>(h, hz);
  kt_w<<<dim3(4, 4, 2), 256, 0, stream>>>(W, Wt);
  kt_w1<<<dim3(4, 2), 256, 0, stream>>>(w1, w1t);
  hipMemsetAsync(wsum, 0, 2 * sizeof(float), stream);
  for (int m = 0; m < NM; ++m) {
    const int* src_m = src + (size_t)m * NE;
    const int* dst_m = dst + (size_t)m * NE;
    // linear part first (el/er needed by scatter)
    k1_mfma<<<dim3(391, 2), 256, 0, stream>>>(hz, Wt + (size_t)m * 65536, feat);
    k1b_elr<<<12500, 256, 0, stream>>>(feat, al + (size_t)m * HDIM, ar + (size_t)m * HDIM, el, er);
    // CSR build + per-edge exp
    hipMemsetAsync(rowptr, 0, (NND + 1) * sizeof(int), stream);
    kc_hist<<<NE / 256, 256, 0, stream>>>(dst_m, rowptr);
    kc_scan<<<1, 1024, 0, stream>>>(rowptr);
    hipMemcpyAsync(cursor, rowptr, NND * sizeof(int), hipMemcpyDeviceToDevice, stream);
    kc_scatter<<<NE / 256, 256, 0, stream>>>(src_m, dst_m, cursor, col, el, er, exps);
    // gather + softmax + elu, then semantic score
    if (m == 0) {
      k3_gather<0><<<12500, 256, 0, stream>>>(rowptr, col, exps, feat, d_out);
      k4_mfma<0><<<391, 256, 0, stream>>>(d_out, w1t, b1, w2, wsum, 0);
    } else {
      k3_gather<1><<<12500, 256, 0, stream>>>(rowptr, col, exps, feat, z1);
      k4_mfma<1><<<391, 256, 0, stream>>>(z1, w1t, b1, w2, wsum, 1);
    }
  }
  k5_out<<<(NND * HDIM / 4) / 256, 256, 0, stream>>>(outp, z1, wsum);
}

// Round 7
// 443.758 us; speedup vs baseline: 3.4959x; 1.3146x over previous
//
#include <hip/hip_runtime.h>
#include <hip/hip_bf16.h>

#define NND 50000
#define NE 800000
#define NM 2
#define INF 256
#define NH 4
#define HDIM 256
#define SHID 128
#define SLOPE 0.2f
#define NB 196          // ceil(NND/256) scan blocks

typedef unsigned short u16;
typedef __attribute__((ext_vector_type(8))) short bf16x8;
typedef __attribute__((ext_vector_type(4))) float f32x4;

__device__ __forceinline__ float us2f(u16 u) {
  union { unsigned int i; float f; } v; v.i = ((unsigned int)u) << 16; return v.f;
}
__device__ __forceinline__ u16 f2us(float f) {
  union { float f; unsigned int i; } v; v.f = f;
  unsigned int r = v.i + 0x7FFFu + ((v.i >> 16) & 1u);
  return (u16)(r >> 16);
}

#define GLDS(g, l) __builtin_amdgcn_global_load_lds( \
    (const __attribute__((address_space(1))) unsigned int*)(g), \
    (__attribute__((address_space(3))) unsigned int*)(l), 16, 0, 0)

// ---------------- convert h f32 -> bf16 ------------------------------------
__global__ __launch_bounds__(256) void kh_cvt(const float* __restrict__ h,
                                              u16* __restrict__ hb) {
  const size_t i = ((size_t)blockIdx.x * 256 + threadIdx.x) * 8;
  float4 a = *(const float4*)(h + i);
  float4 b = *(const float4*)(h + i + 4);
  bf16x8 r;
  r[0] = f2us(a.x); r[1] = f2us(a.y); r[2] = f2us(a.z); r[3] = f2us(a.w);
  r[4] = f2us(b.x); r[5] = f2us(b.y); r[6] = f2us(b.z); r[7] = f2us(b.w);
  *(bf16x8*)(hb + i) = r;
}

// ---------------- W transpose+convert: Wt[m][n][k] = W[m][k][n] ------------
__global__ __launch_bounds__(256) void kt_w(const float* __restrict__ W,
                                            u16* __restrict__ Wt) {
  __shared__ u16 tile[64][65];
  const int t = threadIdx.x;
  const int k0 = blockIdx.x * 64, n0 = blockIdx.y * 64;
  const float* Wm = W + (size_t)blockIdx.z * 65536;
  u16* Wtm = Wt + (size_t)blockIdx.z * 65536;
  const int lr = t >> 2, c0 = (t & 3) * 16;
#pragma unroll
  for (int i = 0; i < 16; ++i)
    tile[lr][c0 + i] = f2us(Wm[(size_t)(k0 + lr) * 256 + n0 + c0 + i]);
  __syncthreads();
#pragma unroll
  for (int i = 0; i < 16; ++i)
    Wtm[(size_t)(n0 + lr) * 256 + k0 + c0 + i] = tile[c0 + i][lr];
}

// w1 [256][128] f32 -> w1t [128][256] bf16
__global__ __launch_bounds__(256) void kt_w1(const float* __restrict__ w1,
                                             u16* __restrict__ w1t) {
  __shared__ u16 tile[64][65];
  const int t = threadIdx.x;
  const int k0 = blockIdx.x * 64, j0 = blockIdx.y * 64;
  const int lr = t >> 2, c0 = (t & 3) * 16;
#pragma unroll
  for (int i = 0; i < 16; ++i)
    tile[lr][c0 + i] = f2us(w1[(size_t)(k0 + lr) * SHID + j0 + c0 + i]);
  __syncthreads();
#pragma unroll
  for (int i = 0; i < 16; ++i)
    w1t[(size_t)(j0 + lr) * 256 + k0 + c0 + i] = tile[c0 + i][lr];
}

// ---------------- CSR build ------------------------------------------------
__global__ __launch_bounds__(256) void kc_hist(const int* __restrict__ dst,
                                               int* __restrict__ rowptr) {
  int e = blockIdx.x * 256 + threadIdx.x;
  if (e < NE) atomicAdd(rowptr + dst[e] + 1, 1);
}

// hierarchical scan of rowptr[1..NND]
__global__ __launch_bounds__(256) void ks1(int* __restrict__ rowptr,
                                           int* __restrict__ bsum) {
  __shared__ int wsums[4];
  const int t = threadIdx.x;
  const int i = blockIdx.x * 256 + t + 1;
  int v = (i <= NND) ? rowptr[i] : 0;
  const int lane = t & 63, wid = t >> 6;
#pragma unroll
  for (int o = 1; o < 64; o <<= 1) {
    int u = __shfl_up(v, o, 64);
    if (lane >= o) v += u;
  }
  if (lane == 63) wsums[wid] = v;
  __syncthreads();
  if (t == 0) {
    int s = 0;
#pragma unroll
    for (int w = 0; w < 4; ++w) { int x = wsums[w]; wsums[w] = s; s += x; }
    bsum[blockIdx.x] = s;                 // block total
  }
  __syncthreads();
  v += wsums[wid];
  if (i <= NND) rowptr[i] = v;            // block-local inclusive scan
}

__global__ __launch_bounds__(256) void ks2(int* __restrict__ bsum) {
  __shared__ int wsums[4];
  const int t = threadIdx.x;
  const int v0 = (t < NB) ? bsum[t] : 0;
  int v = v0;
  const int lane = t & 63, wid = t >> 6;
#pragma unroll
  for (int o = 1; o < 64; o <<= 1) {
    int u = __shfl_up(v, o, 64);
    if (lane >= o) v += u;
  }
  if (lane == 63) wsums[wid] = v;
  __syncthreads();
  if (t == 0) {
    int s = 0;
#pragma unroll
    for (int w = 0; w < 4; ++w) { int x = wsums[w]; wsums[w] = s; s += x; }
  }
  __syncthreads();
  v += wsums[wid];
  if (t < NB) bsum[t] = v - v0;           // exclusive prefix
}

__global__ __launch_bounds__(256) void ks3(int* __restrict__ rowptr,
                                           const int* __restrict__ bsum) {
  const int i = blockIdx.x * 256 + threadIdx.x + 1;
  if (blockIdx.x > 0 && i <= NND) rowptr[i] += bsum[blockIdx.x];
}

// scatter + per-edge attention exp for all 4 heads (CSR order)
__global__ __launch_bounds__(256) void kc_scatter(
    const int* __restrict__ src, const int* __restrict__ dst,
    int* __restrict__ cursor, int* __restrict__ col,
    const float* __restrict__ el, const float* __restrict__ er,
    float* __restrict__ exps)
{
  int e = blockIdx.x * 256 + threadIdx.x;
  if (e >= NE) return;
  int s = src[e], d = dst[e];
  int pos = atomicAdd(cursor + d, 1);
  col[pos] = s;
  float4 a = *(const float4*)(el + s * 4);
  float4 b = *(const float4*)(er + d * 4);
  float4 r;
  float x;
  x = a.x + b.x; x = x > 0.f ? x : SLOPE * x; r.x = __expf(x);
  x = a.y + b.y; x = x > 0.f ? x : SLOPE * x; r.y = __expf(x);
  x = a.z + b.z; x = x > 0.f ? x : SLOPE * x; r.z = __expf(x);
  x = a.w + b.w; x = x > 0.f ? x : SLOPE * x; r.w = __expf(x);
  *(float4*)(exps + (size_t)pos * 4) = r;
}

// ---------------- K1: feat = h @ W[m] via MFMA -----------------------------
__global__ __launch_bounds__(256) void k1_mfma(
    const u16* __restrict__ hb, const u16* __restrict__ Wt,
    u16* __restrict__ feat)
{
  __shared__ u16 As[128 * 32];
  __shared__ u16 Bs[128 * 32];
  const int t = threadIdx.x;
  const int lane = t & 63;
  const int w = t >> 6;
  const int wr = w >> 1, wc = w & 1;
  const int row0 = blockIdx.x * 128;
  const int col0 = blockIdx.y * 128;

  const int sr = t >> 2;
  const int skb = (t & 3) * 8;

  int ra0 = row0 + sr;       if (ra0 >= NND) ra0 = NND - 1;
  int ra1 = row0 + 64 + sr;  if (ra1 >= NND) ra1 = NND - 1;
  const int cb0 = col0 + sr, cb1 = col0 + 64 + sr;

  f32x4 acc[4][4];
#pragma unroll
  for (int i = 0; i < 4; ++i)
#pragma unroll
    for (int j = 0; j < 4; ++j) acc[i][j] = (f32x4){0.f, 0.f, 0.f, 0.f};

  for (int ks = 0; ks < 8; ++ks) {
    const int kb = ks * 32 + skb;
    __syncthreads();
    GLDS(hb + (size_t)ra0 * INF + kb, As + w * 512);
    GLDS(hb + (size_t)ra1 * INF + kb, As + 2048 + w * 512);
    GLDS(Wt + (size_t)cb0 * 256 + kb, Bs + w * 512);
    GLDS(Wt + (size_t)cb1 * 256 + kb, Bs + 2048 + w * 512);
    __syncthreads();
    bf16x8 af[4], bfr[4];
#pragma unroll
    for (int mi = 0; mi < 4; ++mi)
      af[mi] = *(const bf16x8*)(As + (wr * 64 + mi * 16 + (lane & 15)) * 32 + (lane >> 4) * 8);
#pragma unroll
    for (int ni = 0; ni < 4; ++ni)
      bfr[ni] = *(const bf16x8*)(Bs + (wc * 64 + ni * 16 + (lane & 15)) * 32 + (lane >> 4) * 8);
#pragma unroll
    for (int mi = 0; mi < 4; ++mi)
#pragma unroll
      for (int ni = 0; ni < 4; ++ni)
        acc[mi][ni] = __builtin_amdgcn_mfma_f32_16x16x32_bf16(af[mi], bfr[ni], acc[mi][ni], 0, 0, 0);
  }
#pragma unroll
  for (int mi = 0; mi < 4; ++mi) {
    const int r_base = row0 + wr * 64 + mi * 16 + (lane >> 4) * 4;
#pragma unroll
    for (int i = 0; i < 4; ++i) {
      const int r = r_base + i;
      if (r < NND) {
#pragma unroll
        for (int ni = 0; ni < 4; ++ni) {
          const int c = col0 + wc * 64 + ni * 16 + (lane & 15);
          feat[(size_t)r * HDIM + c] = f2us(acc[mi][ni][i]);
        }
      }
    }
  }
}

// ---------------- K1b: el/er from feat -------------------------------------
__global__ __launch_bounds__(256) void k1b_elr(
    const u16* __restrict__ feat,
    const float* __restrict__ al, const float* __restrict__ ar,
    float* __restrict__ el, float* __restrict__ er)
{
  const int n = blockIdx.x * 4 + (threadIdx.x >> 6);
  const int lane = threadIdx.x & 63;
  ushort4 f4 = *(const ushort4*)(feat + (size_t)n * HDIM + lane * 4);
  float4 a4 = *(const float4*)(al + lane * 4);
  float4 r4 = *(const float4*)(ar + lane * 4);
  float fl = us2f(f4.x) * a4.x + us2f(f4.y) * a4.y
           + us2f(f4.z) * a4.z + us2f(f4.w) * a4.w;
  float fr = us2f(f4.x) * r4.x + us2f(f4.y) * r4.y
           + us2f(f4.z) * r4.z + us2f(f4.w) * r4.w;
#pragma unroll
  for (int o = 1; o < 16; o <<= 1) {
    fl += __shfl_xor(fl, o, 64);
    fr += __shfl_xor(fr, o, 64);
  }
  if ((lane & 15) == 0) {
    el[n * 4 + (lane >> 4)] = fl;
    er[n * 4 + (lane >> 4)] = fr;
  }
}

// ---------------- K3: CSR gather -------------------------------------------
template<int OBF>
__global__ __launch_bounds__(256) void k3_gather(
    const int* __restrict__ rowptr, const int* __restrict__ col,
    const float* __restrict__ exps,
    const u16* __restrict__ feat, void* __restrict__ z)
{
  const int d = blockIdx.x * 4 + (threadIdx.x >> 6);
  if (d >= NND) return;
  const int lane = threadIdx.x & 63;
  const int h = lane >> 4;
  const int sub = lane & 15;
  const int beg = rowptr[d], end = rowptr[d + 1];

  float den = 0.f;
  for (int j = beg + sub; j < end; j += 16)
    den += exps[(size_t)j * 4 + h];
#pragma unroll
  for (int o = 1; o < 16; o <<= 1) den += __shfl_xor(den, o, 64);
  const float inv = 1.f / fmaxf(den, 1e-9f);

  float a0 = 0.f, a1 = 0.f, a2 = 0.f, a3 = 0.f;
  int j = beg;
  for (; j + 3 < end; j += 4) {
    int s0 = col[j], s1 = col[j + 1], s2 = col[j + 2], s3 = col[j + 3];
    float p0 = exps[(size_t)j * 4 + h] * inv;
    float p1 = exps[(size_t)(j + 1) * 4 + h] * inv;
    float p2 = exps[(size_t)(j + 2) * 4 + h] * inv;
    float p3 = exps[(size_t)(j + 3) * 4 + h] * inv;
    const ushort4 f0 = *(const ushort4*)(feat + (size_t)s0 * HDIM + lane * 4);
    const ushort4 f1 = *(const ushort4*)(feat + (size_t)s1 * HDIM + lane * 4);
    const ushort4 f2 = *(const ushort4*)(feat + (size_t)s2 * HDIM + lane * 4);
    const ushort4 f3 = *(const ushort4*)(feat + (size_t)s3 * HDIM + lane * 4);
    a0 = fmaf(p0, us2f(f0.x), a0); a1 = fmaf(p0, us2f(f0.y), a1);
    a2 = fmaf(p0, us2f(f0.z), a2); a3 = fmaf(p0, us2f(f0.w), a3);
    a0 = fmaf(p1, us2f(f1.x), a0); a1 = fmaf(p1, us2f(f1.y), a1);
    a2 = fmaf(p1, us2f(f1.z), a2); a3 = fmaf(p1, us2f(f1.w), a3);
    a0 = fmaf(p2, us2f(f2.x), a0); a1 = fmaf(p2, us2f(f2.y), a1);
    a2 = fmaf(p2, us2f(f2.z), a2); a3 = fmaf(p2, us2f(f2.w), a3);
    a0 = fmaf(p3, us2f(f3.x), a0); a1 = fmaf(p3, us2f(f3.y), a1);
    a2 = fmaf(p3, us2f(f3.z), a2); a3 = fmaf(p3, us2f(f3.w), a3);
  }
  for (; j < end; ++j) {
    int s = col[j];
    float p = exps[(size_t)j * 4 + h] * inv;
    const ushort4 f4 = *(const ushort4*)(feat + (size_t)s * HDIM + lane * 4);
    a0 = fmaf(p, us2f(f4.x), a0); a1 = fmaf(p, us2f(f4.y), a1);
    a2 = fmaf(p, us2f(f4.z), a2); a3 = fmaf(p, us2f(f4.w), a3);
  }
  a0 = a0 > 0.f ? a0 : expf(a0) - 1.f;
  a1 = a1 > 0.f ? a1 : expf(a1) - 1.f;
  a2 = a2 > 0.f ? a2 : expf(a2) - 1.f;
  a3 = a3 > 0.f ? a3 : expf(a3) - 1.f;
  const size_t idx = (size_t)d * HDIM + lane * 4;
  if (OBF) {
    ushort4 r; r.x = f2us(a0); r.y = f2us(a1); r.z = f2us(a2); r.w = f2us(a3);
    *(ushort4*)((u16*)z + idx) = r;
  } else {
    float4 r; r.x = a0; r.y = a1; r.z = a2; r.w = a3;
    *(float4*)((float*)z + idx) = r;
  }
}

// ---------------- K4: wsum[m] += sum tanh(z@w1+b1)*w2 via MFMA -------------
template<int ZBF>
__global__ __launch_bounds__(256) void k4_mfma(
    const void* __restrict__ zsrc, const u16* __restrict__ w1t,
    const float* __restrict__ b1, const float* __restrict__ w2,
    float* __restrict__ wsum, int midx)
{
  __shared__ u16 As[128 * 32];
  __shared__ u16 Bs[128 * 32];
  __shared__ float red[4];
  const int t = threadIdx.x;
  const int lane = t & 63;
  const int w = t >> 6;
  const int wr = w >> 1, wc = w & 1;
  const int row0 = blockIdx.x * 128;
  const int sr = t >> 2;
  const int skb = (t & 3) * 8;
  int ra0 = row0 + sr;       if (ra0 >= NND) ra0 = NND - 1;
  int ra1 = row0 + 64 + sr;  if (ra1 >= NND) ra1 = NND - 1;
  const int cb0 = sr, cb1 = 64 + sr;

  f32x4 acc[4][4];
#pragma unroll
  for (int i = 0; i < 4; ++i)
#pragma unroll
    for (int j = 0; j < 4; ++j) acc[i][j] = (f32x4){0.f, 0.f, 0.f, 0.f};

  for (int ks = 0; ks < 8; ++ks) {
    const int kb = ks * 32 + skb;
    __syncthreads();
    if (ZBF) {
      GLDS((const u16*)zsrc + (size_t)ra0 * HDIM + kb, As + w * 512);
      GLDS((const u16*)zsrc + (size_t)ra1 * HDIM + kb, As + 2048 + w * 512);
    } else {
      const float* zf = (const float*)zsrc;
      float4 a = *(const float4*)(zf + (size_t)ra0 * HDIM + kb);
      float4 b = *(const float4*)(zf + (size_t)ra0 * HDIM + kb + 4);
      bf16x8 r;
      r[0] = f2us(a.x); r[1] = f2us(a.y); r[2] = f2us(a.z); r[3] = f2us(a.w);
      r[4] = f2us(b.x); r[5] = f2us(b.y); r[6] = f2us(b.z); r[7] = f2us(b.w);
      *(bf16x8*)(As + sr * 32 + skb) = r;
      a = *(const float4*)(zf + (size_t)ra1 * HDIM + kb);
      b = *(const float4*)(zf + (size_t)ra1 * HDIM + kb + 4);
      r[0] = f2us(a.x); r[1] = f2us(a.y); r[2] = f2us(a.z); r[3] = f2us(a.w);
      r[4] = f2us(b.x); r[5] = f2us(b.y); r[6] = f2us(b.z); r[7] = f2us(b.w);
      *(bf16x8*)(As + (64 + sr) * 32 + skb) = r;
    }
    GLDS(w1t + (size_t)cb0 * 256 + kb, Bs + w * 512);
    GLDS(w1t + (size_t)cb1 * 256 + kb, Bs + 2048 + w * 512);
    __syncthreads();
    bf16x8 af[4], bfr[4];
#pragma unroll
    for (int mi = 0; mi < 4; ++mi)
      af[mi] = *(const bf16x8*)(As + (wr * 64 + mi * 16 + (lane & 15)) * 32 + (lane >> 4) * 8);
#pragma unroll
    for (int ni = 0; ni < 4; ++ni)
      bfr[ni] = *(const bf16x8*)(Bs + (wc * 64 + ni * 16 + (lane & 15)) * 32 + (lane >> 4) * 8);
#pragma unroll
    for (int mi = 0; mi < 4; ++mi)
#pragma unroll
      for (int ni = 0; ni < 4; ++ni)
        acc[mi][ni] = __builtin_amdgcn_mfma_f32_16x16x32_bf16(af[mi], bfr[ni], acc[mi][ni], 0, 0, 0);
  }
  float sum = 0.f;
#pragma unroll
  for (int ni = 0; ni < 4; ++ni) {
    const int c = wc * 64 + ni * 16 + (lane & 15);
    const float b1c = b1[c], w2c = w2[c];
#pragma unroll
    for (int mi = 0; mi < 4; ++mi) {
      const int r_base = row0 + wr * 64 + mi * 16 + (lane >> 4) * 4;
#pragma unroll
      for (int i = 0; i < 4; ++i) {
        if (r_base + i < NND)
          sum += tanhf(acc[mi][ni][i] + b1c) * w2c;
      }
    }
  }
#pragma unroll
  for (int o = 32; o; o >>= 1) sum += __shfl_xor(sum, o, 64);
  if (lane == 0) red[w] = sum;
  __syncthreads();
  if (t == 0) unsafeAtomicAdd(wsum + midx, red[0] + red[1] + red[2] + red[3]);
}

// ---------------- K5: beta=softmax(wsum/N); out = b0*z0 + b1*z1 ------------
__global__ __launch_bounds__(256) void k5_out(
    float* __restrict__ out, const u16* __restrict__ z1,
    const float* __restrict__ wsum)
{
  const int i = blockIdx.x * 256 + threadIdx.x;
  float w0 = wsum[0] * (1.0f / NND);
  float w1v = wsum[1] * (1.0f / NND);
  float mx = fmaxf(w0, w1v);
  float e0 = expf(w0 - mx), e1 = expf(w1v - mx);
  float inv = 1.f / (e0 + e1);
  float b0 = e0 * inv, b1 = e1 * inv;
  float4 a = ((const float4*)out)[i];
  ushort4 zb = ((const ushort4*)z1)[i];
  float4 r;
  r.x = b0 * a.x + b1 * us2f(zb.x);
  r.y = b0 * a.y + b1 * us2f(zb.y);
  r.z = b0 * a.z + b1 * us2f(zb.z);
  r.w = b0 * a.w + b1 * us2f(zb.w);
  ((float4*)out)[i] = r;
}

extern "C" void kernel_launch(void* const* d_in, const int* in_sizes, int n_in,
                              void* d_out, int out_size, void* d_ws, size_t ws_size,
                              hipStream_t stream)
{
  const float* h  = (const float*)d_in[0];
  const int* src  = (const int*)d_in[1];
  const int* dst  = (const int*)d_in[2];
  const float* W  = (const float*)d_in[3];
  const float* al = (const float*)d_in[4];
  const float* ar = (const float*)d_in[5];
  const float* w1 = (const float*)d_in[6];
  const float* b1 = (const float*)d_in[7];
  const float* w2 = (const float*)d_in[8];

  // workspace layout (bytes)
  char* wsb = (char*)d_ws;
  u16*   feat   = (u16*)(wsb);                 // 25,600,000
  u16*   hz     = (u16*)(wsb + 25600000);      // 25,600,000  (bf16 h; z1 aliases)
  float* exps   = (float*)(wsb + 51200000);    // 12,800,000
  int*   col    = (int*)(wsb + 64000000);      //  3,200,000
  u16*   Wt     = (u16*)(wsb + 67200000);      //    262,144
  u16*   w1t    = (u16*)(wsb + 67462144);      //     65,536
  float* el     = (float*)(wsb + 67527680);    //    800,000
  float* er     = (float*)(wsb + 68327680);    //    800,000
  int*   rowptr = (int*)(wsb + 69127680);      //    200,004
  int*   cursor = (int*)(wsb + 69327684);      //    200,000
  float* wsum   = (float*)(wsb + 69527684);    //          8
  int*   bsum   = (int*)(wsb + 69527696);      //        784
  const size_t NEED = 69528480;
  if (ws_size < NEED) {
    hipMemsetAsync(d_out, 0x7F, (size_t)out_size * 4, stream);
    return;
  }
  u16* z1 = hz;        // alias: hz dead after k1_mfma(m=1), z1 written by k3(m=1)
  float* outp = (float*)d_out;

  kh_cvt<<<6250, 256, 0, stream>>>(h, hz);
  kt_w<<<dim3(4, 4, 2), 256, 0, stream>>>(W, Wt);
  kt_w1<<<dim3(4, 2), 256, 0, stream>>>(w1, w1t);
  hipMemsetAsync(wsum, 0, 2 * sizeof(float), stream);
  for (int m = 0; m < NM; ++m) {
    const int* src_m = src + (size_t)m * NE;
    const int* dst_m = dst + (size_t)m * NE;
    // linear part first (el/er needed by scatter)
    k1_mfma<<<dim3(391, 2), 256, 0, stream>>>(hz, Wt + (size_t)m * 65536, feat);
    k1b_elr<<<12500, 256, 0, stream>>>(feat, al + (size_t)m * HDIM, ar + (size_t)m * HDIM, el, er);
    // CSR build (hierarchical scan) + per-edge exp
    hipMemsetAsync(rowptr, 0, (NND + 1) * sizeof(int), stream);
    kc_hist<<<NE / 256, 256, 0, stream>>>(dst_m, rowptr);
    ks1<<<NB, 256, 0, stream>>>(rowptr, bsum);
    ks2<<<1, 256, 0, stream>>>(bsum);
    ks3<<<NB, 256, 0, stream>>>(rowptr, bsum);
    hipMemcpyAsync(cursor, rowptr, NND * sizeof(int), hipMemcpyDeviceToDevice, stream);
    kc_scatter<<<NE / 256, 256, 0, stream>>>(src_m, dst_m, cursor, col, el, er, exps);
    // gather + softmax + elu, then semantic score
    if (m == 0) {
      k3_gather<0><<<12500, 256, 0, stream>>>(rowptr, col, exps, feat, d_out);
      k4_mfma<0><<<391, 256, 0, stream>>>(d_out, w1t, b1, w2, wsum, 0);
    } else {
      k3_gather<1><<<12500, 256, 0, stream>>>(rowptr, col, exps, feat, z1);
      k4_mfma<1><<<391, 256, 0, stream>>>(z1, w1t, b1, w2, wsum, 1);
    }
  }
  k5_out<<<(NND * HDIM / 4) / 256, 256, 0, stream>>>(outp, z1, wsum);
}